// Round 1
// baseline (439.184 us; speedup 1.0000x reference)
//
#include <hip/hip_runtime.h>

typedef __attribute__((ext_vector_type(8))) short short8;
typedef __attribute__((ext_vector_type(4))) float f32x4;
typedef unsigned short ushort_t;

// ---------- helpers ----------
__device__ __forceinline__ unsigned short f2bf(float f) {
  unsigned u = __builtin_bit_cast(unsigned, f);
  u += 0x7FFFu + ((u >> 16) & 1u);   // round-to-nearest-even
  return (unsigned short)(u >> 16);
}

__device__ __forceinline__ void gl_lds16(const void* g, void* l) {
  __builtin_amdgcn_global_load_lds(
      (const __attribute__((address_space(1))) void*)g,
      (__attribute__((address_space(3))) void*)l, 16, 0, 0);
}

// ---------- kernel 1: x (f32) -> bf16 ----------
__global__ __launch_bounds__(256) void cvt_x(const float* __restrict__ x,
                                             ushort_t* __restrict__ xb) {
  size_t i = ((size_t)blockIdx.x * 256 + threadIdx.x) * 8;
  float4 v0 = *(const float4*)(x + i);
  float4 v1 = *(const float4*)(x + i + 4);
  union { ushort_t s[8]; uint4 v; } o;
  o.s[0] = f2bf(v0.x); o.s[1] = f2bf(v0.y); o.s[2] = f2bf(v0.z); o.s[3] = f2bf(v0.w);
  o.s[4] = f2bf(v1.x); o.s[5] = f2bf(v1.y); o.s[6] = f2bf(v1.z); o.s[7] = f2bf(v1.w);
  *(uint4*)(xb + i) = o.v;
}

// ---------- kernel 2: W_eff = W + A@B, stored bf16 ----------
__global__ __launch_bounds__(256) void build_weff(const float* __restrict__ W,
                                                  const float* __restrict__ A,
                                                  const float* __restrict__ B,
                                                  ushort_t* __restrict__ Weff) {
  const int K = 4096, R = 16;
  const int n = blockIdx.y;
  const int k = (blockIdx.x * 256 + threadIdx.x) * 4;
  float4 w = *(const float4*)(W + (size_t)n * K + k);
  float a0 = w.x, a1 = w.y, a2 = w.z, a3 = w.w;
#pragma unroll
  for (int r = 0; r < R; ++r) {
    float a = A[n * R + r];                       // scalar broadcast (uniform n)
    float4 b = *(const float4*)(B + (size_t)r * K + k);
    a0 += a * b.x; a1 += a * b.y; a2 += a * b.z; a3 += a * b.w;
  }
  union { ushort_t s[4]; uint2 v; } o;
  o.s[0] = f2bf(a0); o.s[1] = f2bf(a1); o.s[2] = f2bf(a2); o.s[3] = f2bf(a3);
  *(uint2*)(Weff + (size_t)n * K + k) = o.v;
}

// ---------- kernel 3: C[M][N] = Xb[M][K] * Wb[N][K]^T  (bf16 in, f32 out) ----------
// m97 structure: 128x128 tile, BK=32, 4 waves (2x2), global_load_lds width 16.
__global__ __launch_bounds__(256) void gemm_bt(const ushort_t* __restrict__ Xb,
                                               const ushort_t* __restrict__ Wb,
                                               float* __restrict__ C) {
  const int M = 8192, N = 4096, K = 4096;
  (void)M;
  __shared__ __align__(16) ushort_t As[128 * 32];
  __shared__ __align__(16) ushort_t Bs[128 * 32];

  const int t  = threadIdx.x;
  const int l  = t & 63;
  const int wv = t >> 6;          // wave 0..3
  const int wm = wv >> 1;         // wave row 0..1
  const int wn = wv & 1;          // wave col 0..1
  const int bm = blockIdx.y * 128;
  const int bn = blockIdx.x * 128;

  f32x4 acc[4][4];
#pragma unroll
  for (int i = 0; i < 4; ++i)
#pragma unroll
    for (int j = 0; j < 4; ++j) acc[i][j] = (f32x4)(0.0f);

  // staging addressing: each issue covers 64 rows; lane l -> row +l/4, col (l%4)*8
  const int srow = wv * 16 + (l >> 2);
  const int scol = (l & 3) * 8;
  const ushort_t* ag0 = Xb + (size_t)(bm + srow) * K + scol;
  const ushort_t* ag1 = Xb + (size_t)(bm + 64 + srow) * K + scol;
  const ushort_t* bg0 = Wb + (size_t)(bn + srow) * K + scol;
  const ushort_t* bg1 = Wb + (size_t)(bn + 64 + srow) * K + scol;
  char* adst0 = (char*)As + (size_t)(wv * 16) * 64;        // wave-uniform LDS dest
  char* adst1 = (char*)As + (size_t)(64 + wv * 16) * 64;
  char* bdst0 = (char*)Bs + (size_t)(wv * 16) * 64;
  char* bdst1 = (char*)Bs + (size_t)(64 + wv * 16) * 64;

  // LDS fragment read addresses (loop-invariant)
  const ushort_t* ars[4];
  const ushort_t* brs[4];
#pragma unroll
  for (int mi = 0; mi < 4; ++mi)
    ars[mi] = &As[(size_t)(wm * 64 + mi * 16 + (l & 15)) * 32 + (l >> 4) * 8];
#pragma unroll
  for (int ni = 0; ni < 4; ++ni)
    brs[ni] = &Bs[(size_t)(wn * 64 + ni * 16 + (l & 15)) * 32 + (l >> 4) * 8];

  for (int k0 = 0; k0 < K; k0 += 32) {
    __syncthreads();                       // LDS consumed; safe to overwrite
    gl_lds16(ag0, adst0);
    gl_lds16(ag1, adst1);
    gl_lds16(bg0, bdst0);
    gl_lds16(bg1, bdst1);
    ag0 += 32; ag1 += 32; bg0 += 32; bg1 += 32;
    __syncthreads();                       // staged data visible
    short8 a[4], b[4];
#pragma unroll
    for (int mi = 0; mi < 4; ++mi) a[mi] = *(const short8*)ars[mi];
#pragma unroll
    for (int ni = 0; ni < 4; ++ni) b[ni] = *(const short8*)brs[ni];
#pragma unroll
    for (int mi = 0; mi < 4; ++mi)
#pragma unroll
      for (int ni = 0; ni < 4; ++ni)
        acc[mi][ni] = __builtin_amdgcn_mfma_f32_16x16x32_bf16(a[mi], b[ni],
                                                              acc[mi][ni], 0, 0, 0);
  }

  // epilogue: C/D layout col = lane&15, row = (lane>>4)*4 + j
#pragma unroll
  for (int mi = 0; mi < 4; ++mi) {
#pragma unroll
    for (int ni = 0; ni < 4; ++ni) {
      const int row = bm + wm * 64 + mi * 16 + (l >> 4) * 4;
      const int col = bn + wn * 64 + ni * 16 + (l & 15);
      float* cp = C + (size_t)row * N + col;
#pragma unroll
      for (int j = 0; j < 4; ++j) cp[(size_t)j * N] = acc[mi][ni][j];
    }
  }
}

extern "C" void kernel_launch(void* const* d_in, const int* in_sizes, int n_in,
                              void* d_out, int out_size, void* d_ws, size_t ws_size,
                              hipStream_t stream) {
  const float* x = (const float*)d_in[0];   // [8192, 4096]
  const float* W = (const float*)d_in[1];   // [4096, 4096]
  const float* A = (const float*)d_in[2];   // [4096, 16]
  const float* B = (const float*)d_in[3];   // [16, 4096]
  float* out = (float*)d_out;               // [8192, 4096]

  // ws layout: [0, 64MB) x_bf16 ; [64MB, 96MB) W_eff bf16
  ushort_t* xb = (ushort_t*)d_ws;
  ushort_t* wb = (ushort_t*)((char*)d_ws + (size_t)8192 * 4096 * 2);

  cvt_x<<<16384, 256, 0, stream>>>(x, xb);                 // 33.5M elems / 8 per thread
  dim3 gw(4, 4096);
  build_weff<<<gw, 256, 0, stream>>>(W, A, B, wb);
  dim3 gg(32, 64);                                          // N/128, M/128
  gemm_bt<<<gg, 256, 0, stream>>>(xb, wb, out);
}

// Round 4
// 333.700 us; speedup vs baseline: 1.3161x; 1.3161x over previous
//
#include <hip/hip_runtime.h>

typedef __attribute__((ext_vector_type(8))) short short8;
typedef __attribute__((ext_vector_type(4))) float f32x4;
typedef unsigned short ushort_t;

#define BAR()   __builtin_amdgcn_s_barrier()
#define LGKM0() asm volatile("s_waitcnt lgkmcnt(0)" ::: "memory")
#define VM6()   asm volatile("s_waitcnt vmcnt(6)" ::: "memory")
#define VM0()   asm volatile("s_waitcnt vmcnt(0)" ::: "memory")
#define PRIO(n) __builtin_amdgcn_s_setprio(n)
#define MFMA(a_, b_, c_) __builtin_amdgcn_mfma_f32_16x16x32_bf16(a_, b_, c_, 0, 0, 0)

// ---------- helpers ----------
__device__ __forceinline__ unsigned short f2bf(float f) {
  unsigned u = __builtin_bit_cast(unsigned, f);
  u += 0x7FFFu + ((u >> 16) & 1u);   // round-to-nearest-even
  return (unsigned short)(u >> 16);
}

__device__ __forceinline__ void gl_lds16(const void* g, void* l) {
  __builtin_amdgcn_global_load_lds(
      (const __attribute__((address_space(1))) void*)g,
      (__attribute__((address_space(3))) void*)l, 16, 0, 0);
}

// ---------- kernel 1: x (f32) -> bf16 ----------
__global__ __launch_bounds__(256) void cvt_x(const float* __restrict__ x,
                                             ushort_t* __restrict__ xb) {
  size_t i = ((size_t)blockIdx.x * 256 + threadIdx.x) * 8;
  float4 v0 = *(const float4*)(x + i);
  float4 v1 = *(const float4*)(x + i + 4);
  union { ushort_t s[8]; uint4 v; } o;
  o.s[0] = f2bf(v0.x); o.s[1] = f2bf(v0.y); o.s[2] = f2bf(v0.z); o.s[3] = f2bf(v0.w);
  o.s[4] = f2bf(v1.x); o.s[5] = f2bf(v1.y); o.s[6] = f2bf(v1.z); o.s[7] = f2bf(v1.w);
  *(uint4*)(xb + i) = o.v;
}

// ---------- kernel 2: W_eff = W + A@B, stored bf16 ----------
__global__ __launch_bounds__(256) void build_weff(const float* __restrict__ W,
                                                  const float* __restrict__ A,
                                                  const float* __restrict__ B,
                                                  ushort_t* __restrict__ Weff) {
  const int K = 4096, R = 16;
  const int n = blockIdx.y;
  const int k = (blockIdx.x * 256 + threadIdx.x) * 4;
  float4 w = *(const float4*)(W + (size_t)n * K + k);
  float a0 = w.x, a1 = w.y, a2 = w.z, a3 = w.w;
#pragma unroll
  for (int r = 0; r < R; ++r) {
    float a = A[n * R + r];
    float4 b = *(const float4*)(B + (size_t)r * K + k);
    a0 += a * b.x; a1 += a * b.y; a2 += a * b.z; a3 += a * b.w;
  }
  union { ushort_t s[4]; uint2 v; } o;
  o.s[0] = f2bf(a0); o.s[1] = f2bf(a1); o.s[2] = f2bf(a2); o.s[3] = f2bf(a3);
  *(uint2*)(Weff + (size_t)n * K + k) = o.v;
}

// ---------- kernel 3: 256x256 8-phase bf16 GEMM (m201 structure) ----------
// C[M][N] = Xb[M][K] * Wb[N][K]^T. BM=BN=256, BK=64 (2 k-halves of 32).
// LDS: 2 dbuf x 4 halves (A-k0, A-k1, B-k0, B-k1) x [256 rows][32 cols] bf16 = 128 KiB.
// 8 waves (2M x 4N); per-wave C = 128x64 = acc[8][4] f32x4.
// Per K-tile 4 phases: P1{rd a0-3/k0 + b0-3/k0, stage A-k1(t+1)->buf^1}  Q(m0-3,k0)
//                      P2{rd a4-7/k0,            stage B-k0(t+2)->buf}    Q(m4-7,k0)
//                      P3{rd a0-3/k1 + b0-3/k1,  stage A-k0(t+2)->buf}    Q(m0-3,k1)
//                      P4{rd a4-7/k1,            stage B-k1(t+2)->buf, vmcnt(6)} Q(m4-7,k1)
// vmcnt(6) = 3 half-tiles (2 loads each) in flight; guarantees tile t+1 fully landed.
// st_16x32 swizzle: byte^=((row>>3)&1)<<5, applied to global SOURCE at stage and to
// ds_read address (LDS dest stays linear for global_load_lds — rule 21).

__device__ __forceinline__ void stage_half(const ushort_t* __restrict__ G, int row0, int kc,
                                           ushort_t* half, int tid) {
#pragma unroll
  for (int r = 0; r < 2; ++r) {
    const int idx  = r * 512 + tid;
    const int lrow = idx >> 2;                                  // 0..255
    const int cb   = ((idx & 3) * 16) ^ (((lrow >> 3) & 1) << 5); // pre-swizzled source col (bytes)
    const ushort_t* src = G + (size_t)(row0 + lrow) * 4096 + kc + (cb >> 1);
    char* dst = (char*)half + (size_t)(r * 512 + (tid & ~63)) * 16; // wave-uniform; HW adds lane*16
    gl_lds16(src, dst);
  }
}

__global__ __launch_bounds__(512, 2) void gemm256(const ushort_t* __restrict__ Xb,
                                                  const ushort_t* __restrict__ Wb,
                                                  float* __restrict__ C) {
  const int N = 4096;
  const int NT = 4096 / 64;                 // 64 K-tiles
  __shared__ __align__(16) ushort_t lds[2][4][256 * 32];  // [buf][A0,A1,B0,B1][row][col]

  const int tid = threadIdx.x;
  const int l   = tid & 63;
  const int w   = tid >> 6;
  const int wm  = w >> 2;                   // 0..1
  const int wn  = w & 3;                    // 0..3

  // T1: bijective XCD chunking — 512 blocks = 8 chunks of 8x8 tiles (grid 32x16)
  const int bid = blockIdx.x;
  const int c = bid & 7, q = bid >> 3;
  const int tm = (c >> 1) * 8 + (q >> 3);   // 0..31
  const int tn = (c & 1) * 8 + (q & 7);     // 0..15
  const int bm = tm * 256, bn = tn * 256;

  // fragment LDS byte offsets within a half (swizzled read side)
  const int colb = ((l >> 4) * 16) ^ (((l >> 3) & 1) << 5);
  int aoff[8], boff[4];
#pragma unroll
  for (int mi = 0; mi < 8; ++mi) aoff[mi] = (wm * 128 + mi * 16 + (l & 15)) * 64 + colb;
#pragma unroll
  for (int ni = 0; ni < 4; ++ni) boff[ni] = (wn * 64 + ni * 16 + (l & 15)) * 64 + colb;

  f32x4 acc[8][4];
#pragma unroll
  for (int i = 0; i < 8; ++i)
#pragma unroll
    for (int j = 0; j < 4; ++j) acc[i][j] = (f32x4)(0.0f);

  // prologue: 7 halves (tile0 all + tile1 B-k0,A-k0,B-k1), then vmcnt(6) -> tile0 landed
  stage_half(Wb, bn, 0,  lds[0][2], tid);
  stage_half(Xb, bm, 0,  lds[0][0], tid);
  stage_half(Wb, bn, 32, lds[0][3], tid);
  stage_half(Xb, bm, 32, lds[0][1], tid);
  stage_half(Wb, bn, 64, lds[1][2], tid);
  stage_half(Xb, bm, 64, lds[1][0], tid);
  stage_half(Wb, bn, 96, lds[1][3], tid);
  VM6();
  BAR();

  short8 af0, af1, af2, af3, bf0, bf1, bf2, bf3;

#define LDA(P_, I0_) do { \
    af0 = *(const short8*)((const char*)(P_) + aoff[(I0_) + 0]); \
    af1 = *(const short8*)((const char*)(P_) + aoff[(I0_) + 1]); \
    af2 = *(const short8*)((const char*)(P_) + aoff[(I0_) + 2]); \
    af3 = *(const short8*)((const char*)(P_) + aoff[(I0_) + 3]); \
  } while (0)
#define LDB(P_) do { \
    bf0 = *(const short8*)((const char*)(P_) + boff[0]); \
    bf1 = *(const short8*)((const char*)(P_) + boff[1]); \
    bf2 = *(const short8*)((const char*)(P_) + boff[2]); \
    bf3 = *(const short8*)((const char*)(P_) + boff[3]); \
  } while (0)
#define QUAD(M0_) do { \
    acc[(M0_)+0][0] = MFMA(af0, bf0, acc[(M0_)+0][0]); \
    acc[(M0_)+0][1] = MFMA(af0, bf1, acc[(M0_)+0][1]); \
    acc[(M0_)+0][2] = MFMA(af0, bf2, acc[(M0_)+0][2]); \
    acc[(M0_)+0][3] = MFMA(af0, bf3, acc[(M0_)+0][3]); \
    acc[(M0_)+1][0] = MFMA(af1, bf0, acc[(M0_)+1][0]); \
    acc[(M0_)+1][1] = MFMA(af1, bf1, acc[(M0_)+1][1]); \
    acc[(M0_)+1][2] = MFMA(af1, bf2, acc[(M0_)+1][2]); \
    acc[(M0_)+1][3] = MFMA(af1, bf3, acc[(M0_)+1][3]); \
    acc[(M0_)+2][0] = MFMA(af2, bf0, acc[(M0_)+2][0]); \
    acc[(M0_)+2][1] = MFMA(af2, bf1, acc[(M0_)+2][1]); \
    acc[(M0_)+2][2] = MFMA(af2, bf2, acc[(M0_)+2][2]); \
    acc[(M0_)+2][3] = MFMA(af2, bf3, acc[(M0_)+2][3]); \
    acc[(M0_)+3][0] = MFMA(af3, bf0, acc[(M0_)+3][0]); \
    acc[(M0_)+3][1] = MFMA(af3, bf1, acc[(M0_)+3][1]); \
    acc[(M0_)+3][2] = MFMA(af3, bf2, acc[(M0_)+3][2]); \
    acc[(M0_)+3][3] = MFMA(af3, bf3, acc[(M0_)+3][3]); \
  } while (0)

  int cur = 0;
  for (int t = 0; t < NT; ++t) {
    const ushort_t* A0h = lds[cur][0];
    const ushort_t* A1h = lds[cur][1];
    const ushort_t* B0h = lds[cur][2];
    const ushort_t* B1h = lds[cur][3];
    const int kc2 = (t + 2) * 64;

    // P1
    LDA(A0h, 0); LDB(B0h);
    if (t + 1 < NT) stage_half(Xb, bm, (t + 1) * 64 + 32, lds[cur ^ 1][1], tid);
    BAR(); LGKM0(); PRIO(1);
    QUAD(0);
    PRIO(0); BAR();

    // P2
    LDA(A0h, 4);
    if (t + 2 < NT) stage_half(Wb, bn, kc2, lds[cur][2], tid);
    BAR(); LGKM0(); PRIO(1);
    QUAD(4);
    PRIO(0); BAR();

    // P3
    LDA(A1h, 0); LDB(B1h);
    if (t + 2 < NT) stage_half(Xb, bm, kc2, lds[cur][0], tid);
    BAR(); LGKM0(); PRIO(1);
    QUAD(0);
    PRIO(0); BAR();

    // P4
    LDA(A1h, 4);
    if (t + 2 < NT) stage_half(Wb, bn, kc2 + 32, lds[cur][3], tid);
    if (t + 2 < NT) { VM6(); } else { VM0(); }
    BAR(); LGKM0(); PRIO(1);
    QUAD(4);
    PRIO(0); BAR();

    cur ^= 1;
  }

  // epilogue: C/D layout col = lane&15, row = (lane>>4)*4 + j
  const int erow = bm + wm * 128 + (l >> 4) * 4;
  const int ecol = bn + wn * 64 + (l & 15);
#pragma unroll
  for (int mi = 0; mi < 8; ++mi) {
#pragma unroll
    for (int ni = 0; ni < 4; ++ni) {
      float* cp = C + (size_t)(erow + mi * 16) * N + ecol + ni * 16;
#pragma unroll
      for (int j = 0; j < 4; ++j) cp[(size_t)j * N] = acc[mi][ni][j];
    }
  }
}

extern "C" void kernel_launch(void* const* d_in, const int* in_sizes, int n_in,
                              void* d_out, int out_size, void* d_ws, size_t ws_size,
                              hipStream_t stream) {
  const float* x = (const float*)d_in[0];   // [8192, 4096]
  const float* W = (const float*)d_in[1];   // [4096, 4096]
  const float* A = (const float*)d_in[2];   // [4096, 16]
  const float* B = (const float*)d_in[3];   // [16, 4096]
  float* out = (float*)d_out;               // [8192, 4096]

  ushort_t* xb = (ushort_t*)d_ws;                                   // 64 MB
  ushort_t* wb = (ushort_t*)((char*)d_ws + (size_t)8192 * 4096 * 2); // 32 MB

  cvt_x<<<16384, 256, 0, stream>>>(x, xb);
  dim3 gw(4, 4096);
  build_weff<<<gw, 256, 0, stream>>>(W, A, B, wb);
  gemm256<<<512, 512, 0, stream>>>(xb, wb, out);  // grid 32x16 tiles, XCD-chunked
}

// Round 5
// 333.609 us; speedup vs baseline: 1.3165x; 1.0003x over previous
//
#include <hip/hip_runtime.h>

typedef __attribute__((ext_vector_type(8))) short short8;
typedef __attribute__((ext_vector_type(4))) float f32x4;
typedef unsigned short ushort_t;

#define BAR()   __builtin_amdgcn_s_barrier()
#define VM0()   asm volatile("s_waitcnt vmcnt(0)" ::: "memory")
#define SB()    __builtin_amdgcn_sched_barrier(0)
#define PRIO(n) __builtin_amdgcn_s_setprio(n)
#define MFMA(a_, b_, c_) __builtin_amdgcn_mfma_f32_16x16x32_bf16(a_, b_, c_, 0, 0, 0)

// ---------- helpers ----------
__device__ __forceinline__ unsigned short f2bf(float f) {
  unsigned u = __builtin_bit_cast(unsigned, f);
  u += 0x7FFFu + ((u >> 16) & 1u);   // round-to-nearest-even
  return (unsigned short)(u >> 16);
}

__device__ __forceinline__ void gl_lds16(const void* g, void* l) {
  __builtin_amdgcn_global_load_lds(
      (const __attribute__((address_space(1))) void*)g,
      (__attribute__((address_space(3))) void*)l, 16, 0, 0);
}

// ---------- kernel 1: x (f32) -> bf16 ----------
__global__ __launch_bounds__(256) void cvt_x(const float* __restrict__ x,
                                             ushort_t* __restrict__ xb) {
  size_t i = ((size_t)blockIdx.x * 256 + threadIdx.x) * 8;
  float4 v0 = *(const float4*)(x + i);
  float4 v1 = *(const float4*)(x + i + 4);
  union { ushort_t s[8]; uint4 v; } o;
  o.s[0] = f2bf(v0.x); o.s[1] = f2bf(v0.y); o.s[2] = f2bf(v0.z); o.s[3] = f2bf(v0.w);
  o.s[4] = f2bf(v1.x); o.s[5] = f2bf(v1.y); o.s[6] = f2bf(v1.z); o.s[7] = f2bf(v1.w);
  *(uint4*)(xb + i) = o.v;
}

// ---------- kernel 2: W_eff = W + A@B, stored bf16 ----------
__global__ __launch_bounds__(256) void build_weff(const float* __restrict__ W,
                                                  const float* __restrict__ A,
                                                  const float* __restrict__ B,
                                                  ushort_t* __restrict__ Weff) {
  const int K = 4096, R = 16;
  const int n = blockIdx.y;
  const int k = (blockIdx.x * 256 + threadIdx.x) * 4;
  float4 w = *(const float4*)(W + (size_t)n * K + k);
  float a0 = w.x, a1 = w.y, a2 = w.z, a3 = w.w;
#pragma unroll
  for (int r = 0; r < R; ++r) {
    float a = A[n * R + r];
    float4 b = *(const float4*)(B + (size_t)r * K + k);
    a0 += a * b.x; a1 += a * b.y; a2 += a * b.z; a3 += a * b.w;
  }
  union { ushort_t s[4]; uint2 v; } o;
  o.s[0] = f2bf(a0); o.s[1] = f2bf(a1); o.s[2] = f2bf(a2); o.s[3] = f2bf(a3);
  *(uint2*)(Weff + (size_t)n * K + k) = o.v;
}

// ---------- kernel 3: 256x256 bf16 GEMM, 1-barrier/K-tile pipelined ----------
// C[M][N] = Xb[M][K] * Wb[N][K]^T. BM=BN=256, BK=64 (2 k-halves of 32).
// LDS: 2 dbuf x 4 halves (A-k0, A-k1, B-k0, B-k1) x [256 r][32 c] bf16 = 128 KiB.
// 8 waves (2M x 4N); per-wave C = 128x64 = acc[8][4] f32x4; 64 MFMA/wave/K-tile.
// Strict double-buffer: tile t reads buf cur ONLY; stages for t+1 write buf cur^1
// ONLY -> no intra-tile WAR -> single barrier per K-tile. Per-wave program order
// (pinned by sched_barrier(0)): [8 stage-issues][r1:8 rd][r2:4 rd] Q1 [r3:8 rd]
// Q2 [r4:4 rd] Q3 Q4 [vmcnt(0)] BAR. Compiler inserts counted lgkmcnt before
// each quad's first use (DS in-order). Waves desync within the tile -> one
// wave's LDS reads overlap another's MFMA; setprio(1) favors the MFMA waves.
// vmcnt(0) drain is ~free: stage loads issued ~3000 cy earlier (HBM ~900 cy).
// st_16x32 swizzle unchanged (bank conflicts measured 0): pre-swizzled global
// SOURCE at stage + same XOR on read addr; LDS dest linear (rule 21).

__device__ __forceinline__ void stage_half(const ushort_t* __restrict__ G, int row0, int kc,
                                           ushort_t* half, int tid) {
#pragma unroll
  for (int r = 0; r < 2; ++r) {
    const int idx  = r * 512 + tid;
    const int lrow = idx >> 2;                                    // 0..255
    const int cb   = ((idx & 3) * 16) ^ (((lrow >> 3) & 1) << 5); // pre-swizzled source col (bytes)
    const ushort_t* src = G + (size_t)(row0 + lrow) * 4096 + kc + (cb >> 1);
    char* dst = (char*)half + (size_t)(r * 512 + (tid & ~63)) * 16; // wave-uniform; HW adds lane*16
    gl_lds16(src, dst);
  }
}

__global__ __launch_bounds__(512) void gemm256(const ushort_t* __restrict__ Xb,
                                               const ushort_t* __restrict__ Wb,
                                               float* __restrict__ C) {
  const int N = 4096;
  const int NT = 4096 / 64;                 // 64 K-tiles
  __shared__ __align__(16) ushort_t lds[2][4][256 * 32];  // [buf][A0,A1,B0,B1][row][col]

  const int tid = threadIdx.x;
  const int l   = tid & 63;
  const int w   = tid >> 6;
  const int wm  = w >> 2;                   // 0..1
  const int wn  = w & 3;                    // 0..3

  // T1: bijective XCD chunking — 512 blocks = 8 chunks of 8x8 tiles (grid 32x16)
  const int bid = blockIdx.x;
  const int c = bid & 7, q = bid >> 3;
  const int tm = (c >> 1) * 8 + (q >> 3);   // 0..31
  const int tn = (c & 1) * 8 + (q & 7);     // 0..15
  const int bm = tm * 256, bn = tn * 256;

  // fragment LDS byte offsets within a half (swizzled read side)
  const int colb = ((l >> 4) * 16) ^ (((l >> 3) & 1) << 5);
  int aoff[8], boff[4];
#pragma unroll
  for (int mi = 0; mi < 8; ++mi) aoff[mi] = (wm * 128 + mi * 16 + (l & 15)) * 64 + colb;
#pragma unroll
  for (int ni = 0; ni < 4; ++ni) boff[ni] = (wn * 64 + ni * 16 + (l & 15)) * 64 + colb;

  f32x4 acc[8][4];
#pragma unroll
  for (int i = 0; i < 8; ++i)
#pragma unroll
    for (int j = 0; j < 4; ++j) acc[i][j] = (f32x4)(0.0f);

  // prologue: stage tile 0 into buf 0, drain, barrier
  stage_half(Wb, bn, 0,  lds[0][2], tid);
  stage_half(Xb, bm, 0,  lds[0][0], tid);
  stage_half(Wb, bn, 32, lds[0][3], tid);
  stage_half(Xb, bm, 32, lds[0][1], tid);
  VM0();
  BAR();

  short8 a1_0, a1_1, a1_2, a1_3;   // a-set 1 (m0-3 of current k-half)
  short8 a2_0, a2_1, a2_2, a2_3;   // a-set 2 (m4-7)
  short8 b1_0, b1_1, b1_2, b1_3;   // b-set k0
  short8 b2_0, b2_1, b2_2, b2_3;   // b-set k1

#define RD_A1(P_) do { \
    a1_0 = *(const short8*)((const char*)(P_) + aoff[0]); \
    a1_1 = *(const short8*)((const char*)(P_) + aoff[1]); \
    a1_2 = *(const short8*)((const char*)(P_) + aoff[2]); \
    a1_3 = *(const short8*)((const char*)(P_) + aoff[3]); \
  } while (0)
#define RD_A2(P_) do { \
    a2_0 = *(const short8*)((const char*)(P_) + aoff[4]); \
    a2_1 = *(const short8*)((const char*)(P_) + aoff[5]); \
    a2_2 = *(const short8*)((const char*)(P_) + aoff[6]); \
    a2_3 = *(const short8*)((const char*)(P_) + aoff[7]); \
  } while (0)
#define RD_B(P_, B0_, B1_, B2_, B3_) do { \
    B0_ = *(const short8*)((const char*)(P_) + boff[0]); \
    B1_ = *(const short8*)((const char*)(P_) + boff[1]); \
    B2_ = *(const short8*)((const char*)(P_) + boff[2]); \
    B3_ = *(const short8*)((const char*)(P_) + boff[3]); \
  } while (0)
#define QUAD(M0_, A0_, A1_, A2_, A3_, B0_, B1_, B2_, B3_) do { \
    acc[(M0_)+0][0] = MFMA(A0_, B0_, acc[(M0_)+0][0]); \
    acc[(M0_)+0][1] = MFMA(A0_, B1_, acc[(M0_)+0][1]); \
    acc[(M0_)+0][2] = MFMA(A0_, B2_, acc[(M0_)+0][2]); \
    acc[(M0_)+0][3] = MFMA(A0_, B3_, acc[(M0_)+0][3]); \
    acc[(M0_)+1][0] = MFMA(A1_, B0_, acc[(M0_)+1][0]); \
    acc[(M0_)+1][1] = MFMA(A1_, B1_, acc[(M0_)+1][1]); \
    acc[(M0_)+1][2] = MFMA(A1_, B2_, acc[(M0_)+1][2]); \
    acc[(M0_)+1][3] = MFMA(A1_, B3_, acc[(M0_)+1][3]); \
    acc[(M0_)+2][0] = MFMA(A2_, B0_, acc[(M0_)+2][0]); \
    acc[(M0_)+2][1] = MFMA(A2_, B1_, acc[(M0_)+2][1]); \
    acc[(M0_)+2][2] = MFMA(A2_, B2_, acc[(M0_)+2][2]); \
    acc[(M0_)+2][3] = MFMA(A2_, B3_, acc[(M0_)+2][3]); \
    acc[(M0_)+3][0] = MFMA(A3_, B0_, acc[(M0_)+3][0]); \
    acc[(M0_)+3][1] = MFMA(A3_, B1_, acc[(M0_)+3][1]); \
    acc[(M0_)+3][2] = MFMA(A3_, B2_, acc[(M0_)+3][2]); \
    acc[(M0_)+3][3] = MFMA(A3_, B3_, acc[(M0_)+3][3]); \
  } while (0)

  int cur = 0;
  for (int t = 0; t < NT; ++t) {
    const ushort_t* A0h = lds[cur][0];
    const ushort_t* A1h = lds[cur][1];
    const ushort_t* B0h = lds[cur][2];
    const ushort_t* B1h = lds[cur][3];

    // stage tile t+1 into buf cur^1 (vm loads get the whole tile to land)
    if (t + 1 < NT) {
      const int kc = (t + 1) * 64;
      stage_half(Wb, bn, kc,      lds[cur ^ 1][2], tid);
      stage_half(Xb, bm, kc,      lds[cur ^ 1][0], tid);
      stage_half(Wb, bn, kc + 32, lds[cur ^ 1][3], tid);
      stage_half(Xb, bm, kc + 32, lds[cur ^ 1][1], tid);
    }

    // r1 (Q1 operands) + r2 (Q2's a-set) issued up front
    RD_A1(A0h);
    RD_B(B0h, b1_0, b1_1, b1_2, b1_3);
    RD_A2(A0h);
    SB();
    PRIO(1); QUAD(0, a1_0, a1_1, a1_2, a1_3, b1_0, b1_1, b1_2, b1_3); PRIO(0);  // Q1: m0-3,k0
    SB();
    RD_A1(A1h);                                // r3: k1 a0-3 (aset1 free after Q1)
    RD_B(B1h, b2_0, b2_1, b2_2, b2_3);         //     k1 b0-3
    SB();
    PRIO(1); QUAD(4, a2_0, a2_1, a2_2, a2_3, b1_0, b1_1, b1_2, b1_3); PRIO(0);  // Q2: m4-7,k0
    SB();
    RD_A2(A1h);                                // r4: k1 a4-7 (aset2 free after Q2)
    SB();
    PRIO(1); QUAD(0, a1_0, a1_1, a1_2, a1_3, b2_0, b2_1, b2_2, b2_3); PRIO(0);  // Q3: m0-3,k1
    SB();
    PRIO(1); QUAD(4, a2_0, a2_1, a2_2, a2_3, b2_0, b2_1, b2_2, b2_3); PRIO(0);  // Q4: m4-7,k1
    SB();
    VM0();          // tile t+1 fully landed in cur^1 (loads issued ~3000 cy ago)
    BAR();          // all waves done reading cur; cur^1 ready
    cur ^= 1;
  }

  // epilogue: C/D layout col = lane&15, row = (lane>>4)*4 + j
  const int erow = bm + wm * 128 + (l >> 4) * 4;
  const int ecol = bn + wn * 64 + (l & 15);
#pragma unroll
  for (int mi = 0; mi < 8; ++mi) {
#pragma unroll
    for (int ni = 0; ni < 4; ++ni) {
      float* cp = C + (size_t)(erow + mi * 16) * N + ecol + ni * 16;
#pragma unroll
      for (int j = 0; j < 4; ++j) cp[(size_t)j * N] = acc[mi][ni][j];
    }
  }
}

extern "C" void kernel_launch(void* const* d_in, const int* in_sizes, int n_in,
                              void* d_out, int out_size, void* d_ws, size_t ws_size,
                              hipStream_t stream) {
  const float* x = (const float*)d_in[0];   // [8192, 4096]
  const float* W = (const float*)d_in[1];   // [4096, 4096]
  const float* A = (const float*)d_in[2];   // [4096, 16]
  const float* B = (const float*)d_in[3];   // [16, 4096]
  float* out = (float*)d_out;               // [8192, 4096]

  ushort_t* xb = (ushort_t*)d_ws;                                    // 64 MB
  ushort_t* wb = (ushort_t*)((char*)d_ws + (size_t)8192 * 4096 * 2); // 32 MB

  cvt_x<<<16384, 256, 0, stream>>>(x, xb);
  dim3 gw(4, 4096);
  build_weff<<<gw, 256, 0, stream>>>(W, A, B, wb);
  gemm256<<<512, 512, 0, stream>>>(xb, wb, out);  // grid 32x16 tiles, XCD-chunked
}